// Round 2
// baseline (228.424 us; speedup 1.0000x reference)
//
#include <hip/hip_runtime.h>

#define EPS 1e-8f
#define LN_EPS 1e-5f
#define NROWS 8192
#define SLEN 4096
#define PROBS_OFF 2097152   // 8192*256

// One block per row: features -> encoder -> LayerNorm -> head -> softmax.
// Row-independent pipeline, so full fusion removes the second launch, the
// combined-feature global round-trip, and the 16KB row LDS (direct global
// loads; the 2.25x neighborhood overlap is L1-absorbed, HBM traffic stays 1x).
__global__ __launch_bounds__(256) void k_fused(
    const float* __restrict__ prices,
    const float* __restrict__ enc_w, const float* __restrict__ enc_b,
    const float* __restrict__ enc_g, const float* __restrict__ enc_bt,
    const float* __restrict__ w1, const float* __restrict__ b1,
    const float* __restrict__ w2, const float* __restrict__ b2,
    float* __restrict__ out)
{
    __shared__ float red[16];      // per-wave partials: [wave][sum,sq,ts]
    __shared__ float tailv[2];     // p_last, p_m10
    __shared__ float rfl[256];     // regime features (fp32) for the head
    __shared__ float hpart[4][64]; // head partial dot products per K-chunk

    const int t = threadIdx.x;
    const int b = blockIdx.x;
    const int lane = t & 63, wv = t >> 6;
    const float* rowp = prices + (size_t)b * SLEN;
    const int p0 = t * 16;

    // ---- phase A: per-row time-series features ----
    // thread t owns positions [16t, 16t+16); needs s[16t-20 .. 16t+16)
    float seg[16], prev[20];
    #pragma unroll
    for (int i = 0; i < 4; ++i)
        *(float4*)(seg + 4 * i) = *(const float4*)(rowp + p0 + 4 * i);
    #pragma unroll
    for (int i = 0; i < 5; ++i) {
        int base = p0 - 20 + 4 * i;              // byte addr 64t-80+16i: 16B aligned
        float4 pv;
        if (base >= 0) pv = *(const float4*)(rowp + base);
        else pv = make_float4(0.f, 0.f, 0.f, 0.f);
        *(float4*)(prev + 4 * i) = pv;
    }

    // rolling 20-window sum; zero-padded prev makes the row edge branch-free
    float W = seg[0];
    #pragma unroll
    for (int j = 1; j < 20; ++j) W += prev[j];

    float x = seg[0];
    float sum = x, sq = x * x;
    float cnt = fminf((float)(p0 + 1), 20.0f);
    float sma = W * __builtin_amdgcn_rcpf(cnt);
    float ts = (x - sma) * __builtin_amdgcn_rcpf(sma + EPS);
    #pragma unroll
    for (int j = 1; j < 16; ++j) {
        x = seg[j];
        W += x - prev[j];                        // prev[j] == s[p0+j-20] (0 if OOB)
        sum += x;
        sq = fmaf(x, x, sq);
        float c2 = fminf((float)(p0 + j + 1), 20.0f);
        float sm = W * __builtin_amdgcn_rcpf(c2);
        ts += (x - sm) * __builtin_amdgcn_rcpf(sm + EPS);
    }

    #pragma unroll
    for (int off = 32; off > 0; off >>= 1) {
        sum += __shfl_xor(sum, off);
        sq  += __shfl_xor(sq,  off);
        ts  += __shfl_xor(ts,  off);
    }
    if (lane == 0) { red[wv * 4] = sum; red[wv * 4 + 1] = sq; red[wv * 4 + 2] = ts; }
    if (t == 255) { tailv[0] = seg[15]; tailv[1] = seg[6]; }  // s[4095], s[4086]
    __syncthreads();

    // every thread computes the 4 combined features (cheap, avoids a broadcast pass)
    float S = red[0] + red[4] + red[8]  + red[12];
    float Q = red[1] + red[5] + red[9]  + red[13];
    float T = red[2] + red[6] + red[10] + red[14];
    float mean = S * (1.0f / 4096.0f);
    float var  = fmaxf((Q - 4096.0f * mean * mean) * (1.0f / 4095.0f), 0.0f);
    float p_last = tailv[0], p_m10 = tailv[1];
    float c0 = T * (1.0f / 4096.0f);
    float c1 = (p_last - p_m10) / (p_m10 + EPS);
    float c2f = (p_last - mean) / (mean + EPS);
    float c3 = sqrtf(var) / (mean + EPS);

    // ---- phase B: encoder (4 -> 256) + relu + LayerNorm(64) ----
    // wave = e-group, lane = o; enc_w layout [e][i][o]
    float v = enc_b[t];
    v = fmaf(c0, enc_w[wv * 256 + lane],       v);
    v = fmaf(c1, enc_w[wv * 256 + 64 + lane],  v);
    v = fmaf(c2f, enc_w[wv * 256 + 128 + lane], v);
    v = fmaf(c3, enc_w[wv * 256 + 192 + lane], v);
    v = fmaxf(v, 0.0f);
    float sm = v;
    #pragma unroll
    for (int off = 32; off > 0; off >>= 1) sm += __shfl_xor(sm, off);
    float mu = sm * (1.0f / 64.0f);
    float d = v - mu;
    float vs = d * d;
    #pragma unroll
    for (int off = 32; off > 0; off >>= 1) vs += __shfl_xor(vs, off);
    float y = fmaf(d * rsqrtf(vs * (1.0f / 64.0f) + LN_EPS), enc_g[t], enc_bt[t]);
    out[(size_t)b * 256 + t] = y;    // regime_features (fp32)
    rfl[t] = y;
    __syncthreads();

    // ---- phase C: h = rf @ w1, K split across waves (fp32 VALU) ----
    // wave wv handles k in [64wv, 64wv+64), lane = output j; w1 reads coalesced
    {
        float acc = 0.0f;
        const float* w1p = w1 + (size_t)(wv * 64) * 64 + lane;
        #pragma unroll 8
        for (int k = 0; k < 64; ++k)
            acc = fmaf(rfl[wv * 64 + k], w1p[k * 64], acc);
        hpart[wv][lane] = acc;
    }
    __syncthreads();

    // ---- phase D: finish head + logits + softmax (wave 0 only) ----
    if (t < 64) {
        float h = hpart[0][t] + hpart[1][t] + hpart[2][t] + hpart[3][t] + b1[t];
        h = fmaxf(h, 0.0f);
        float4 wrow = *(const float4*)(w2 + t * 4);
        float l0 = h * wrow.x, l1 = h * wrow.y, l2 = h * wrow.z, l3 = h * wrow.w;
        #pragma unroll
        for (int off = 32; off > 0; off >>= 1) {
            l0 += __shfl_xor(l0, off);
            l1 += __shfl_xor(l1, off);
            l2 += __shfl_xor(l2, off);
            l3 += __shfl_xor(l3, off);
        }
        if (t == 0) {
            l0 += b2[0]; l1 += b2[1]; l2 += b2[2]; l3 += b2[3];
            float mx = fmaxf(fmaxf(l0, l1), fmaxf(l2, l3));
            float e0 = __expf(l0 - mx), e1 = __expf(l1 - mx);
            float e2 = __expf(l2 - mx), e3 = __expf(l3 - mx);
            float inv = 1.0f / (e0 + e1 + e2 + e3);
            float4 pr = make_float4(e0 * inv, e1 * inv, e2 * inv, e3 * inv);
            *(float4*)(out + PROBS_OFF + (size_t)b * 4) = pr;
        }
    }
}

extern "C" void kernel_launch(void* const* d_in, const int* in_sizes, int n_in,
                              void* d_out, int out_size, void* d_ws, size_t ws_size,
                              hipStream_t stream) {
    const float* prices  = (const float*)d_in[0];
    const float* enc_w   = (const float*)d_in[1];
    const float* enc_b   = (const float*)d_in[2];
    const float* enc_g   = (const float*)d_in[3];
    const float* enc_bt  = (const float*)d_in[4];
    const float* head_w1 = (const float*)d_in[5];
    const float* head_b1 = (const float*)d_in[6];
    const float* head_w2 = (const float*)d_in[7];
    const float* head_b2 = (const float*)d_in[8];
    float* out = (float*)d_out;

    k_fused<<<NROWS, 256, 0, stream>>>(prices, enc_w, enc_b, enc_g, enc_bt,
                                       head_w1, head_b1, head_w2, head_b2, out);
}

// Round 3
// 227.779 us; speedup vs baseline: 1.0028x; 1.0028x over previous
//
#include <hip/hip_runtime.h>

#define EPS 1e-8f
#define LN_EPS 1e-5f
#define NROWS 8192
#define SLEN 4096
#define PROBS_OFF 2097152   // 8192*256

typedef __attribute__((ext_vector_type(8))) short bf16x8;
typedef __attribute__((ext_vector_type(4))) float f32x4;

__device__ __forceinline__ short f2bf(float f) {
    unsigned u = __float_as_uint(f);
    unsigned r = (u + 0x7FFFu + ((u >> 16) & 1u)) >> 16;  // RNE
    return (short)r;
}

// ---------------- K1: wave-per-row features, zero block-sync ----------------
// Lane l owns row elements [64l, 64l+64) in registers; rolling-20 window is
// in-lane (prev tail zero-padded); only wave-level shuffle reductions.
__global__ __launch_bounds__(256) void k_feat(const float* __restrict__ prices,
                                              float* __restrict__ comb) {
    const int t = threadIdx.x;
    const int lane = t & 63, wv = t >> 6;
    const int b = blockIdx.x * 4 + wv;
    const float* rowp = prices + (size_t)b * SLEN;
    const int p0 = lane * 64;

    float seg[64], prev[20];
    #pragma unroll
    for (int i = 0; i < 16; ++i)
        *(float4*)(seg + 4 * i) = *(const float4*)(rowp + p0 + 4 * i);
    #pragma unroll
    for (int i = 0; i < 5; ++i) {
        int base = p0 - 20 + 4 * i;               // 16B aligned; <0 only for lane 0
        float4 pv;
        if (base >= 0) pv = *(const float4*)(rowp + base);
        else pv = make_float4(0.f, 0.f, 0.f, 0.f);
        *(float4*)(prev + 4 * i) = pv;
    }

    // W = rolling sum of window ending at p0: seg[0] + prev[1..19]
    float W = seg[0];
    #pragma unroll
    for (int j = 1; j < 20; ++j) W += prev[j];

    float x = seg[0];
    float sum = x, sq = x * x;
    float cnt = fminf((float)(p0 + 1), 20.0f);
    float sma = W * __builtin_amdgcn_rcpf(cnt);
    float ts = (x - sma) * __builtin_amdgcn_rcpf(sma + EPS);
    #pragma unroll
    for (int j = 1; j < 64; ++j) {
        x = seg[j];
        float old = (j < 20) ? prev[j] : seg[j - 20];  // compile-time select
        W += x - old;
        sum += x;
        sq = fmaf(x, x, sq);
        float c2 = fminf((float)(p0 + j + 1), 20.0f);  // 20 except lane 0 head
        float sm = W * __builtin_amdgcn_rcpf(c2);
        ts += (x - sm) * __builtin_amdgcn_rcpf(sm + EPS);
    }

    #pragma unroll
    for (int off = 32; off > 0; off >>= 1) {
        sum += __shfl_xor(sum, off);
        sq  += __shfl_xor(sq,  off);
        ts  += __shfl_xor(ts,  off);
    }
    float p_last = __shfl(seg[63], 63);   // element 4095
    float p_m10  = __shfl(seg[54], 63);   // element 4086

    if (lane == 0) {
        float mean = sum * (1.0f / 4096.0f);
        float var  = fmaxf((sq - 4096.0f * mean * mean) * (1.0f / 4095.0f), 0.0f);
        float4 c;
        c.x = ts * (1.0f / 4096.0f);
        c.y = (p_last - p_m10) / (p_m10 + EPS);
        c.z = (p_last - mean) / (mean + EPS);
        c.w = sqrtf(var) / (mean + EPS);
        *(float4*)(comb + (size_t)b * 4) = c;
    }
}

// ---------------- K2: encoder + LN + head (MFMA) + softmax ----------------
#define ROWS 32

__global__ __launch_bounds__(256) void k_head(
    const float* __restrict__ combg, float* __restrict__ out,
    const float* __restrict__ enc_w, const float* __restrict__ enc_b,
    const float* __restrict__ enc_g, const float* __restrict__ enc_bt,
    const float* __restrict__ w1, const float* __restrict__ b1,
    const float* __restrict__ w2, const float* __restrict__ b2)
{
    __shared__ float comb[ROWS][4];
    __shared__ short rfb[ROWS][264];   // bf16 rf tile, +8 pad
    __shared__ float hbuf[ROWS][68];   // padded

    const int t = threadIdx.x;
    const int r0 = blockIdx.x * ROWS;
    const int lane = t & 63, wave = t >> 6;
    const int l15 = lane & 15, q = lane >> 4;

    if (t < ROWS * 4)
        comb[t >> 2][t & 3] = combg[(size_t)(r0 + (t >> 2)) * 4 + (t & 3)];

    // B-frags: wave w owns cols [16w,16w+16); B layout n=lane&15, k=q*8+j per k-tile
    bf16x8 bfrag[8];
    #pragma unroll
    for (int kt = 0; kt < 8; ++kt) {
        #pragma unroll
        for (int j = 0; j < 8; ++j) {
            int k = kt * 32 + q * 8 + j;
            bfrag[kt][j] = f2bf(w1[k * 64 + wave * 16 + l15]);
        }
    }

    const float ew0 = enc_w[wave * 256 + lane];
    const float ew1v = enc_w[wave * 256 + 64 + lane];
    const float ew2v = enc_w[wave * 256 + 128 + lane];
    const float ew3v = enc_w[wave * 256 + 192 + lane];
    const float ebv = enc_b[t], egv = enc_g[t], btv = enc_bt[t];

    __syncthreads();

    // encoder + relu + LayerNorm (wave == e-group of 64)
    for (int r = 0; r < ROWS; ++r) {
        float4 cb = *(const float4*)comb[r];
        float v = fmaf(cb.x, ew0, fmaf(cb.y, ew1v, fmaf(cb.z, ew2v, fmaf(cb.w, ew3v, ebv))));
        v = fmaxf(v, 0.0f);
        float sm = v;
        #pragma unroll
        for (int off = 32; off > 0; off >>= 1) sm += __shfl_xor(sm, off);
        float mu = sm * (1.0f / 64.0f);
        float d = v - mu;
        float vs = d * d;
        #pragma unroll
        for (int off = 32; off > 0; off >>= 1) vs += __shfl_xor(vs, off);
        float y = fmaf(d * rsqrtf(vs * (1.0f / 64.0f) + LN_EPS), egv, btv);
        out[(size_t)(r0 + r) * 256 + t] = y;       // regime_features fp32
        rfb[r][t] = f2bf(y);
    }
    __syncthreads();

    // h = rf @ w1 via 16x16x32 bf16 MFMA; wave handles m-tiles {0,1} for its n-tile
    f32x4 acc0 = {0.f, 0.f, 0.f, 0.f}, acc1 = {0.f, 0.f, 0.f, 0.f};
    #pragma unroll
    for (int kt = 0; kt < 8; ++kt) {
        bf16x8 a0 = *(const bf16x8*)&rfb[l15][kt * 32 + q * 8];
        bf16x8 a1 = *(const bf16x8*)&rfb[16 + l15][kt * 32 + q * 8];
        acc0 = __builtin_amdgcn_mfma_f32_16x16x32_bf16(a0, bfrag[kt], acc0, 0, 0, 0);
        acc1 = __builtin_amdgcn_mfma_f32_16x16x32_bf16(a1, bfrag[kt], acc1, 0, 0, 0);
    }

    const int col = wave * 16 + l15;
    const float b1v = b1[col];
    #pragma unroll
    for (int rg = 0; rg < 4; ++rg) {
        hbuf[q * 4 + rg][col]      = fmaxf(acc0[rg] + b1v, 0.0f);
        hbuf[16 + q * 4 + rg][col] = fmaxf(acc1[rg] + b1v, 0.0f);
    }
    __syncthreads();

    // logits + softmax (quad per row)
    if (t < 128) {
        int r = t >> 2, c = t & 3;
        float lg = b2[c];
        #pragma unroll
        for (int j = 0; j < 64; ++j) lg = fmaf(hbuf[r][j], w2[j * 4 + c], lg);
        float mx = fmaxf(lg, __shfl_xor(lg, 1, 4));
        mx = fmaxf(mx, __shfl_xor(mx, 2, 4));
        float ex = __expf(lg - mx);
        float s2 = ex + __shfl_xor(ex, 1, 4);
        s2 += __shfl_xor(s2, 2, 4);
        out[PROBS_OFF + (size_t)(r0 + r) * 4 + c] = ex / s2;
    }
}

extern "C" void kernel_launch(void* const* d_in, const int* in_sizes, int n_in,
                              void* d_out, int out_size, void* d_ws, size_t ws_size,
                              hipStream_t stream) {
    const float* prices  = (const float*)d_in[0];
    const float* enc_w   = (const float*)d_in[1];
    const float* enc_b   = (const float*)d_in[2];
    const float* enc_g   = (const float*)d_in[3];
    const float* enc_bt  = (const float*)d_in[4];
    const float* head_w1 = (const float*)d_in[5];
    const float* head_b1 = (const float*)d_in[6];
    const float* head_w2 = (const float*)d_in[7];
    const float* head_b2 = (const float*)d_in[8];
    float* out  = (float*)d_out;
    float* comb = (float*)d_ws;    // 8192*4 floats staged in workspace

    k_feat<<<NROWS / 4, 256, 0, stream>>>(prices, comb);
    k_head<<<NROWS / ROWS, 256, 0, stream>>>(comb, out, enc_w, enc_b, enc_g, enc_bt,
                                             head_w1, head_b1, head_w2, head_b2);
}

// Round 4
// 222.632 us; speedup vs baseline: 1.0260x; 1.0231x over previous
//
#include <hip/hip_runtime.h>

#define EPS 1e-8f
#define LN_EPS 1e-5f
#define NROWS 8192
#define SLEN 4096
#define PROBS_OFF 2097152   // 8192*256

typedef __attribute__((ext_vector_type(8))) short bf16x8;
typedef __attribute__((ext_vector_type(4))) float f32x4;

__device__ __forceinline__ short f2bf(float f) {
    unsigned u = __float_as_uint(f);
    unsigned r = (u + 0x7FFFu + ((u >> 16) & 1u)) >> 16;  // RNE
    return (short)r;
}

// ---------------- K1: block-per-row features, scratch-proof ----------------
// NO private arrays anywhere (R1-R3 all kept seg[]/prev[] locals accessed via
// casted float4* -> mem2reg failed -> scratch; VGPR_Count=20 was the tell).
// All window state is named scalars; row staged in LDS with +1-per-16 padding
// (addr = idx + idx/16 => stride-17 thread access, gcd(17,32)=1, conflict-free).
__global__ __launch_bounds__(256) void k_feat(const float* __restrict__ prices,
                                              float* __restrict__ comb) {
    __shared__ float sld[SLEN + (SLEN >> 4)];   // 4352 floats = 17 KB
    __shared__ float red[12];

    const int t = threadIdx.x;
    const int b = blockIdx.x;
    const int lane = t & 63, wv = t >> 6;
    const float4* rowp4 = (const float4*)(prices + (size_t)b * SLEN);

#define SL(i) sld[(i) + ((i) >> 4)]

    // coalesced stage: lane-consecutive float4s -> padded LDS scalars
    #pragma unroll
    for (int i = 0; i < 4; ++i) {
        float4 v = rowp4[i * 256 + t];
        int idx = (i * 256 + t) * 4;
        int a = idx + (idx >> 4);
        sld[a] = v.x; sld[a + 1] = v.y; sld[a + 2] = v.z; sld[a + 3] = v.w;
    }
    __syncthreads();

    // thread t owns positions [16t, 16t+16); rolling window sum W in a scalar
    const int p0 = t * 16;
    float W = 0.0f;
    #pragma unroll
    for (int jj = 1; jj < 20; ++jj) {          // prev tail s[p0-19 .. p0-1], zero-padded
        int oi = p0 - 20 + jj;
        float pv = SL(oi < 0 ? 0 : oi);
        W += (oi >= 0) ? pv : 0.0f;
    }

    float sum = 0.0f, sq = 0.0f, ts = 0.0f;
    #pragma unroll
    for (int j = 0; j < 16; ++j) {
        float x = SL(p0 + j);
        if (j == 0) {
            W += x;                            // window ending at p0 complete
        } else {
            int oi = p0 + j - 20;
            float ov = SL(oi < 0 ? 0 : oi);
            W += x - ((oi >= 0) ? ov : 0.0f);  // drop s[p0+j-20], add s[p0+j]
        }
        sum += x;
        sq = fmaf(x, x, sq);
        float c = fminf((float)(p0 + j + 1), 20.0f);
        float sm = W * __builtin_amdgcn_rcpf(c);
        ts += (x - sm) * __builtin_amdgcn_rcpf(sm + EPS);
    }

    #pragma unroll
    for (int off = 32; off > 0; off >>= 1) {
        sum += __shfl_xor(sum, off);
        sq  += __shfl_xor(sq,  off);
        ts  += __shfl_xor(ts,  off);
    }
    if (lane == 0) { red[wv * 3] = sum; red[wv * 3 + 1] = sq; red[wv * 3 + 2] = ts; }
    __syncthreads();

    if (t == 0) {
        float S = red[0] + red[3] + red[6] + red[9];
        float Q = red[1] + red[4] + red[7] + red[10];
        float T = red[2] + red[5] + red[8] + red[11];
        float mean = S * (1.0f / 4096.0f);
        float var  = fmaxf((Q - 4096.0f * mean * mean) * (1.0f / 4095.0f), 0.0f);
        float p_last = SL(4095);
        float p_m10  = SL(4086);
        float4 c;
        c.x = T * (1.0f / 4096.0f);
        c.y = (p_last - p_m10) / (p_m10 + EPS);
        c.z = (p_last - mean) / (mean + EPS);
        c.w = sqrtf(var) / (mean + EPS);
        *(float4*)(comb + (size_t)b * 4) = c;
    }
#undef SL
}

// ---------------- K2: encoder + LN + head (MFMA) + softmax ----------------
#define ROWS 32

__global__ __launch_bounds__(256) void k_head(
    const float* __restrict__ combg, float* __restrict__ out,
    const float* __restrict__ enc_w, const float* __restrict__ enc_b,
    const float* __restrict__ enc_g, const float* __restrict__ enc_bt,
    const float* __restrict__ w1, const float* __restrict__ b1,
    const float* __restrict__ w2, const float* __restrict__ b2)
{
    __shared__ float comb[ROWS][4];
    __shared__ short rfb[ROWS][264];   // bf16 rf tile, +8 pad
    __shared__ float hbuf[ROWS][68];   // padded

    const int t = threadIdx.x;
    const int r0 = blockIdx.x * ROWS;
    const int lane = t & 63, wave = t >> 6;
    const int l15 = lane & 15, q = lane >> 4;

    if (t < ROWS * 4)
        comb[t >> 2][t & 3] = combg[(size_t)(r0 + (t >> 2)) * 4 + (t & 3)];

    // B-frags: wave w owns cols [16w,16w+16); B layout n=lane&15, k=q*8+j per k-tile
    bf16x8 bfrag[8];
    #pragma unroll
    for (int kt = 0; kt < 8; ++kt) {
        #pragma unroll
        for (int j = 0; j < 8; ++j) {
            int k = kt * 32 + q * 8 + j;
            bfrag[kt][j] = f2bf(w1[k * 64 + wave * 16 + l15]);
        }
    }

    const float ew0 = enc_w[wave * 256 + lane];
    const float ew1v = enc_w[wave * 256 + 64 + lane];
    const float ew2v = enc_w[wave * 256 + 128 + lane];
    const float ew3v = enc_w[wave * 256 + 192 + lane];
    const float ebv = enc_b[t], egv = enc_g[t], btv = enc_bt[t];

    __syncthreads();

    // encoder + relu + LayerNorm (wave == e-group of 64)
    for (int r = 0; r < ROWS; ++r) {
        float4 cb = *(const float4*)comb[r];
        float v = fmaf(cb.x, ew0, fmaf(cb.y, ew1v, fmaf(cb.z, ew2v, fmaf(cb.w, ew3v, ebv))));
        v = fmaxf(v, 0.0f);
        float sm = v;
        #pragma unroll
        for (int off = 32; off > 0; off >>= 1) sm += __shfl_xor(sm, off);
        float mu = sm * (1.0f / 64.0f);
        float d = v - mu;
        float vs = d * d;
        #pragma unroll
        for (int off = 32; off > 0; off >>= 1) vs += __shfl_xor(vs, off);
        float y = fmaf(d * rsqrtf(vs * (1.0f / 64.0f) + LN_EPS), egv, btv);
        out[(size_t)(r0 + r) * 256 + t] = y;       // regime_features fp32
        rfb[r][t] = f2bf(y);
    }
    __syncthreads();

    // h = rf @ w1 via 16x16x32 bf16 MFMA; wave handles m-tiles {0,1} for its n-tile
    f32x4 acc0 = {0.f, 0.f, 0.f, 0.f}, acc1 = {0.f, 0.f, 0.f, 0.f};
    #pragma unroll
    for (int kt = 0; kt < 8; ++kt) {
        bf16x8 a0 = *(const bf16x8*)&rfb[l15][kt * 32 + q * 8];
        bf16x8 a1 = *(const bf16x8*)&rfb[16 + l15][kt * 32 + q * 8];
        acc0 = __builtin_amdgcn_mfma_f32_16x16x32_bf16(a0, bfrag[kt], acc0, 0, 0, 0);
        acc1 = __builtin_amdgcn_mfma_f32_16x16x32_bf16(a1, bfrag[kt], acc1, 0, 0, 0);
    }

    const int col = wave * 16 + l15;
    const float b1v = b1[col];
    #pragma unroll
    for (int rg = 0; rg < 4; ++rg) {
        hbuf[q * 4 + rg][col]      = fmaxf(acc0[rg] + b1v, 0.0f);
        hbuf[16 + q * 4 + rg][col] = fmaxf(acc1[rg] + b1v, 0.0f);
    }
    __syncthreads();

    // logits + softmax (quad per row)
    if (t < 128) {
        int r = t >> 2, c = t & 3;
        float lg = b2[c];
        #pragma unroll
        for (int j = 0; j < 64; ++j) lg = fmaf(hbuf[r][j], w2[j * 4 + c], lg);
        float mx = fmaxf(lg, __shfl_xor(lg, 1, 4));
        mx = fmaxf(mx, __shfl_xor(mx, 2, 4));
        float ex = __expf(lg - mx);
        float s2 = ex + __shfl_xor(ex, 1, 4);
        s2 += __shfl_xor(s2, 2, 4);
        out[PROBS_OFF + (size_t)(r0 + r) * 4 + c] = ex / s2;
    }
}

extern "C" void kernel_launch(void* const* d_in, const int* in_sizes, int n_in,
                              void* d_out, int out_size, void* d_ws, size_t ws_size,
                              hipStream_t stream) {
    const float* prices  = (const float*)d_in[0];
    const float* enc_w   = (const float*)d_in[1];
    const float* enc_b   = (const float*)d_in[2];
    const float* enc_g   = (const float*)d_in[3];
    const float* enc_bt  = (const float*)d_in[4];
    const float* head_w1 = (const float*)d_in[5];
    const float* head_b1 = (const float*)d_in[6];
    const float* head_w2 = (const float*)d_in[7];
    const float* head_b2 = (const float*)d_in[8];
    float* out  = (float*)d_out;
    float* comb = (float*)d_ws;    // 8192*4 floats staged in workspace

    k_feat<<<NROWS, 256, 0, stream>>>(prices, comb);
    k_head<<<NROWS / ROWS, 256, 0, stream>>>(comb, out, enc_w, enc_b, enc_g, enc_bt,
                                             head_w1, head_b1, head_w2, head_b2);
}